// Round 1
// baseline (327.773 us; speedup 1.0000x reference)
//
#include <hip/hip_runtime.h>
#include <hip/hip_bf16.h>

typedef __bf16 bf16x8 __attribute__((ext_vector_type(8)));
typedef float f32x4 __attribute__((ext_vector_type(4)));

#define GN   1024
#define BATCH 64
#define CIN  256
#define COUT 256

// ---------------------------------------------------------------------------
// Kernel 1: transpose + convert  x[b][i][g] (f32)  ->  xT[b][g][i] (bf16)
// 32x32 LDS tile transpose, coalesced both sides.
// ---------------------------------------------------------------------------
__global__ __launch_bounds__(256) void k_transpose_convert(
    const float* __restrict__ x, ushort* __restrict__ xT)
{
  __shared__ float tile[32][33];  // +1 pad: conflict-free transpose
  const int g0 = blockIdx.x * 32;
  const int i0 = blockIdx.y * 32;
  const int b  = blockIdx.z;
  const int t  = threadIdx.x;

  const float* xb = x + (size_t)b * CIN * GN;
#pragma unroll
  for (int p = 0; p < 4; ++p) {
    int ii = p * 8 + (t >> 5);
    int gg = t & 31;
    tile[ii][gg] = xb[(size_t)(i0 + ii) * GN + g0 + gg];
  }
  __syncthreads();

  ushort* xTb = xT + (size_t)b * GN * CIN;
#pragma unroll
  for (int p = 0; p < 2; ++p) {
    int rr = p * 16 + (t >> 4);
    int cc = (t & 15) * 2;
    float f0 = tile[cc][rr];
    float f1 = tile[cc + 1][rr];
    __hip_bfloat16 h0 = __float2bfloat16(f0);
    __hip_bfloat16 h1 = __float2bfloat16(f1);
    ushort2 uv;
    uv.x = *reinterpret_cast<ushort*>(&h0);
    uv.y = *reinterpret_cast<ushort*>(&h1);
    *reinterpret_cast<ushort2*>(&xTb[(size_t)(g0 + rr) * CIN + i0 + cc]) = uv;
  }
}

// ---------------------------------------------------------------------------
// Kernel 2: per-group GEMM.  One workgroup per g.
//   out[b][o][g] = sum_i xT[b][g][i] * W[g][o][i] + bias[g][o]
// M=64 (b), N=256 (o, 64 per wave), K=256.
// A staged in LDS (XOR-swizzled), B (W) streamed global->reg->bf16.
// mfma_f32_16x16x32_bf16; C/D: col=lane&15, row=(lane>>4)*4+reg  [m89].
// ---------------------------------------------------------------------------
__global__ __launch_bounds__(256) void k_group_gemm(
    const ushort* __restrict__ xT, const float* __restrict__ W,
    const float* __restrict__ bias, float* __restrict__ out)
{
  const int g    = blockIdx.x;
  const int tid  = threadIdx.x;
  const int wave = tid >> 6;
  const int lane = tid & 63;

  __shared__ __align__(16) ushort lA[BATCH * CIN];  // 32 KB

  // ---- stage A: xT[b][g][0..255] -> LDS rows, XOR-swizzled in i ----
#pragma unroll
  for (int r = 0; r < 8; ++r) {
    int b = r * 8 + (tid >> 5);
    int i = (tid & 31) * 8;
    int4 v = *reinterpret_cast<const int4*>(xT + ((size_t)b * GN + g) * CIN + i);
    *reinterpret_cast<int4*>(&lA[b * CIN + (i ^ ((b & 7) << 3))]) = v;
  }
  __syncthreads();

  const int oc = (wave << 6) + (lane & 15);  // this lane's o (n-tile adds n*16)
  const int kq = (lane >> 4) << 3;           // per-lane k offset: (lane>>4)*8

  const float* wptr[4];
#pragma unroll
  for (int n = 0; n < 4; ++n)
    wptr[n] = W + ((size_t)g * COUT + oc + n * 16) * CIN + kq;

  f32x4 acc[4][4];
#pragma unroll
  for (int m = 0; m < 4; ++m)
#pragma unroll
    for (int n = 0; n < 4; ++n)
      acc[m][n] = {0.f, 0.f, 0.f, 0.f};

  // register prefetch depth 1 on B
  float4 bnext[4][2];
#pragma unroll
  for (int n = 0; n < 4; ++n) {
    bnext[n][0] = *reinterpret_cast<const float4*>(wptr[n]);
    bnext[n][1] = *reinterpret_cast<const float4*>(wptr[n] + 4);
  }

#pragma unroll
  for (int ks = 0; ks < 8; ++ks) {
    float4 bcur[4][2];
#pragma unroll
    for (int n = 0; n < 4; ++n) {
      bcur[n][0] = bnext[n][0];
      bcur[n][1] = bnext[n][1];
    }
    if (ks < 7) {
#pragma unroll
      for (int n = 0; n < 4; ++n) {
        bnext[n][0] = *reinterpret_cast<const float4*>(wptr[n] + (ks + 1) * 32);
        bnext[n][1] = *reinterpret_cast<const float4*>(wptr[n] + (ks + 1) * 32 + 4);
      }
    }

    bf16x8 bfr[4];
#pragma unroll
    for (int n = 0; n < 4; ++n) {
      bfr[n][0] = (__bf16)bcur[n][0].x;
      bfr[n][1] = (__bf16)bcur[n][0].y;
      bfr[n][2] = (__bf16)bcur[n][0].z;
      bfr[n][3] = (__bf16)bcur[n][0].w;
      bfr[n][4] = (__bf16)bcur[n][1].x;
      bfr[n][5] = (__bf16)bcur[n][1].y;
      bfr[n][6] = (__bf16)bcur[n][1].z;
      bfr[n][7] = (__bf16)bcur[n][1].w;
    }

    bf16x8 afr[4];
    const int i0 = ks * 32 + kq;
#pragma unroll
    for (int m = 0; m < 4; ++m) {
      int row = m * 16 + (lane & 15);
      afr[m] = *reinterpret_cast<const bf16x8*>(
          &lA[row * CIN + (i0 ^ ((row & 7) << 3))]);
    }

#pragma unroll
    for (int m = 0; m < 4; ++m)
#pragma unroll
      for (int n = 0; n < 4; ++n)
        acc[m][n] = __builtin_amdgcn_mfma_f32_16x16x32_bf16(
            afr[m], bfr[n], acc[m][n], 0, 0, 0);
  }

  // ---- epilogue: bias + scattered stores to out[b][o][g] ----
  float bv[4];
#pragma unroll
  for (int n = 0; n < 4; ++n) bv[n] = bias[g * COUT + oc + n * 16];

#pragma unroll
  for (int m = 0; m < 4; ++m) {
#pragma unroll
    for (int n = 0; n < 4; ++n) {
      int o = oc + n * 16;
#pragma unroll
      for (int j = 0; j < 4; ++j) {
        int b = m * 16 + ((lane >> 4) << 2) + j;
        out[((size_t)b * COUT + o) * GN + g] = acc[m][n][j] + bv[n];
      }
    }
  }
}

// ---------------------------------------------------------------------------
extern "C" void kernel_launch(void* const* d_in, const int* in_sizes, int n_in,
                              void* d_out, int out_size, void* d_ws, size_t ws_size,
                              hipStream_t stream) {
  const float* x  = (const float*)d_in[0];
  const float* W  = (const float*)d_in[1];
  const float* bs = (const float*)d_in[2];
  float* out      = (float*)d_out;
  ushort* xT      = (ushort*)d_ws;  // 64*1024*256*2 = 33.5 MB

  dim3 grid1(GN / 32, CIN / 32, BATCH);
  k_transpose_convert<<<grid1, 256, 0, stream>>>(x, xT);
  k_group_gemm<<<GN, 256, 0, stream>>>(xT, W, bs, out);
}

// Round 2
// 123.426 us; speedup vs baseline: 2.6556x; 2.6556x over previous
//
#include <hip/hip_runtime.h>
#include <hip/hip_bf16.h>

typedef __bf16 bf16x8 __attribute__((ext_vector_type(8)));
typedef float f32x4 __attribute__((ext_vector_type(4)));

#define GN   1024
#define BATCH 64
#define CIN  256
#define COUT 256

// ---------------------------------------------------------------------------
// Kernel 1: transpose + convert  x[b][i][g] (f32)  ->  xT[b][g][i] (bf16)
// ---------------------------------------------------------------------------
__global__ __launch_bounds__(256) void k_transpose_convert(
    const float* __restrict__ x, ushort* __restrict__ xT)
{
  __shared__ float tile[32][33];
  const int g0 = blockIdx.x * 32;
  const int i0 = blockIdx.y * 32;
  const int b  = blockIdx.z;
  const int t  = threadIdx.x;

  const float* xb = x + (size_t)b * CIN * GN;
#pragma unroll
  for (int p = 0; p < 4; ++p) {
    int ii = p * 8 + (t >> 5);
    int gg = t & 31;
    tile[ii][gg] = xb[(size_t)(i0 + ii) * GN + g0 + gg];
  }
  __syncthreads();

  ushort* xTb = xT + (size_t)b * GN * CIN;
#pragma unroll
  for (int p = 0; p < 2; ++p) {
    int rr = p * 16 + (t >> 4);
    int cc = (t & 15) * 2;
    __hip_bfloat16 h0 = __float2bfloat16(tile[cc][rr]);
    __hip_bfloat16 h1 = __float2bfloat16(tile[cc + 1][rr]);
    ushort2 uv;
    uv.x = *reinterpret_cast<ushort*>(&h0);
    uv.y = *reinterpret_cast<ushort*>(&h1);
    *reinterpret_cast<ushort2*>(&xTb[(size_t)(g0 + rr) * CIN + i0 + cc]) = uv;
  }
}

// ---------------------------------------------------------------------------
// Kernel 2: per-group GEMM.  One workgroup per g.
// A (xT) staged in LDS (XOR-swizzled), W streamed global->reg->bf16.
// Epilogue: if use_ws, coalesced bf16 stores to outT[b][g][o];
//           else legacy f32 scatter to out[b][o][g].
// ---------------------------------------------------------------------------
__global__ __launch_bounds__(256) void k_group_gemm(
    const ushort* __restrict__ xT, const float* __restrict__ W,
    const float* __restrict__ bias, float* __restrict__ out,
    ushort* __restrict__ outT, int use_ws)
{
  const int g    = blockIdx.x;
  const int tid  = threadIdx.x;
  const int wave = tid >> 6;
  const int lane = tid & 63;

  __shared__ __align__(16) ushort lA[BATCH * CIN];  // 32 KB

#pragma unroll
  for (int r = 0; r < 8; ++r) {
    int b = r * 8 + (tid >> 5);
    int i = (tid & 31) * 8;
    int4 v = *reinterpret_cast<const int4*>(xT + ((size_t)b * GN + g) * CIN + i);
    *reinterpret_cast<int4*>(&lA[b * CIN + (i ^ ((b & 7) << 3))]) = v;
  }
  __syncthreads();

  const int oc = (wave << 6) + (lane & 15);
  const int kq = (lane >> 4) << 3;

  const float* wptr[4];
#pragma unroll
  for (int n = 0; n < 4; ++n)
    wptr[n] = W + ((size_t)g * COUT + oc + n * 16) * CIN + kq;

  f32x4 acc[4][4];
#pragma unroll
  for (int m = 0; m < 4; ++m)
#pragma unroll
    for (int n = 0; n < 4; ++n)
      acc[m][n] = {0.f, 0.f, 0.f, 0.f};

  float4 bnext[4][2];
#pragma unroll
  for (int n = 0; n < 4; ++n) {
    bnext[n][0] = *reinterpret_cast<const float4*>(wptr[n]);
    bnext[n][1] = *reinterpret_cast<const float4*>(wptr[n] + 4);
  }

#pragma unroll
  for (int ks = 0; ks < 8; ++ks) {
    float4 bcur[4][2];
#pragma unroll
    for (int n = 0; n < 4; ++n) {
      bcur[n][0] = bnext[n][0];
      bcur[n][1] = bnext[n][1];
    }
    if (ks < 7) {
#pragma unroll
      for (int n = 0; n < 4; ++n) {
        bnext[n][0] = *reinterpret_cast<const float4*>(wptr[n] + (ks + 1) * 32);
        bnext[n][1] = *reinterpret_cast<const float4*>(wptr[n] + (ks + 1) * 32 + 4);
      }
    }

    bf16x8 bfr[4];
#pragma unroll
    for (int n = 0; n < 4; ++n) {
      bfr[n][0] = (__bf16)bcur[n][0].x;
      bfr[n][1] = (__bf16)bcur[n][0].y;
      bfr[n][2] = (__bf16)bcur[n][0].z;
      bfr[n][3] = (__bf16)bcur[n][0].w;
      bfr[n][4] = (__bf16)bcur[n][1].x;
      bfr[n][5] = (__bf16)bcur[n][1].y;
      bfr[n][6] = (__bf16)bcur[n][1].z;
      bfr[n][7] = (__bf16)bcur[n][1].w;
    }

    bf16x8 afr[4];
    const int i0 = ks * 32 + kq;
#pragma unroll
    for (int m = 0; m < 4; ++m) {
      int row = m * 16 + (lane & 15);
      afr[m] = *reinterpret_cast<const bf16x8*>(
          &lA[row * CIN + (i0 ^ ((row & 7) << 3))]);
    }

#pragma unroll
    for (int m = 0; m < 4; ++m)
#pragma unroll
      for (int n = 0; n < 4; ++n)
        acc[m][n] = __builtin_amdgcn_mfma_f32_16x16x32_bf16(
            afr[m], bfr[n], acc[m][n], 0, 0, 0);
  }

  float bv[4];
#pragma unroll
  for (int n = 0; n < 4; ++n) bv[n] = bias[g * COUT + oc + n * 16];

  if (use_ws) {
    // coalesced bf16 stores: outT[b][g][o], 16 lanes -> 16 consecutive o
#pragma unroll
    for (int m = 0; m < 4; ++m) {
#pragma unroll
      for (int n = 0; n < 4; ++n) {
        int o = oc + n * 16;
#pragma unroll
        for (int j = 0; j < 4; ++j) {
          int b = m * 16 + ((lane >> 4) << 2) + j;
          __hip_bfloat16 h = __float2bfloat16(acc[m][n][j] + bv[n]);
          outT[((size_t)b * GN + g) * COUT + o] = *reinterpret_cast<ushort*>(&h);
        }
      }
    }
  } else {
    // legacy scatter fallback (ws too small)
#pragma unroll
    for (int m = 0; m < 4; ++m) {
#pragma unroll
      for (int n = 0; n < 4; ++n) {
        int o = oc + n * 16;
#pragma unroll
        for (int j = 0; j < 4; ++j) {
          int b = m * 16 + ((lane >> 4) << 2) + j;
          out[((size_t)b * COUT + o) * GN + g] = acc[m][n][j] + bv[n];
        }
      }
    }
  }
}

// ---------------------------------------------------------------------------
// Kernel 3: transpose  outT[b][g][o] (bf16)  ->  out[b][o][g] (f32)
// ---------------------------------------------------------------------------
__global__ __launch_bounds__(256) void k_transpose_out(
    const ushort* __restrict__ outT, float* __restrict__ out)
{
  __shared__ ushort tile[32][33];
  const int g0 = blockIdx.x * 32;
  const int o0 = blockIdx.y * 32;
  const int b  = blockIdx.z;
  const int t  = threadIdx.x;

  const ushort* src = outT + (size_t)b * GN * COUT;
#pragma unroll
  for (int p = 0; p < 4; ++p) {
    int gl = p * 8 + (t >> 5);
    int ol = t & 31;
    tile[gl][ol] = src[(size_t)(g0 + gl) * COUT + o0 + ol];
  }
  __syncthreads();

  float* dst = out + (size_t)b * COUT * GN;
#pragma unroll
  for (int p = 0; p < 4; ++p) {
    int ol = p * 8 + (t >> 5);
    int gl = t & 31;
    uint u = (uint)tile[gl][ol] << 16;
    dst[(size_t)(o0 + ol) * GN + g0 + gl] = *reinterpret_cast<float*>(&u);
  }
}

// ---------------------------------------------------------------------------
extern "C" void kernel_launch(void* const* d_in, const int* in_sizes, int n_in,
                              void* d_out, int out_size, void* d_ws, size_t ws_size,
                              hipStream_t stream) {
  const float* x  = (const float*)d_in[0];
  const float* W  = (const float*)d_in[1];
  const float* bs = (const float*)d_in[2];
  float* out      = (float*)d_out;

  const size_t xT_elems  = (size_t)BATCH * GN * CIN;   // 16.8M ushort = 33.5 MB
  const size_t oT_elems  = (size_t)BATCH * GN * COUT;  // 16.8M ushort = 33.5 MB
  const bool use_ws = ws_size >= (xT_elems + oT_elems) * sizeof(ushort);

  ushort* xT   = (ushort*)d_ws;
  ushort* outT = xT + xT_elems;

  dim3 grid1(GN / 32, CIN / 32, BATCH);
  k_transpose_convert<<<grid1, 256, 0, stream>>>(x, xT);
  k_group_gemm<<<GN, 256, 0, stream>>>(xT, W, bs, out,
                                       use_ws ? outT : nullptr,
                                       use_ws ? 1 : 0);
  if (use_ws) {
    dim3 grid3(GN / 32, COUT / 32, BATCH);
    k_transpose_out<<<grid3, 256, 0, stream>>>(outT, out);
  }
}

// Round 3
// 122.619 us; speedup vs baseline: 2.6731x; 1.0066x over previous
//
#include <hip/hip_runtime.h>
#include <hip/hip_bf16.h>

typedef __bf16 bf16x8 __attribute__((ext_vector_type(8)));
typedef float f32x4 __attribute__((ext_vector_type(4)));

#define GN   1024
#define BATCH 64
#define CIN  256
#define COUT 256

static __device__ __forceinline__ ushort f2bf(float f) {
  __hip_bfloat16 h = __float2bfloat16(f);
  return *reinterpret_cast<ushort*>(&h);
}
static __device__ __forceinline__ float bf2f(ushort u) {
  uint v = (uint)u << 16;
  return *reinterpret_cast<float*>(&v);
}

// ---------------------------------------------------------------------------
// Kernel 1: transpose + convert  x[b][i][g] (f32)  ->  xT[b][g][i] (bf16)
// 64x64 tile; float4 loads (16B/lane), ushort4 stores (8B/lane).
// LDS tile [64][65]: bank ≡ (row+col)%32 → 2 lanes/bank both phases (free).
// ---------------------------------------------------------------------------
__global__ __launch_bounds__(256) void k_transpose_convert(
    const float* __restrict__ x, ushort* __restrict__ xT)
{
  __shared__ float tile[64][65];
  const int g0 = blockIdx.x * 64;
  const int i0 = blockIdx.y * 64;
  const int b  = blockIdx.z;
  const int t  = threadIdx.x;
  const int a  = t & 15;   // column group (x4)
  const int r  = t >> 4;   // row within pass

  const float* xb = x + (size_t)b * CIN * GN;
#pragma unroll
  for (int p = 0; p < 4; ++p) {
    int ii = p * 16 + r;
    float4 v = *reinterpret_cast<const float4*>(
        &xb[(size_t)(i0 + ii) * GN + g0 + a * 4]);
    tile[ii][a * 4 + 0] = v.x;
    tile[ii][a * 4 + 1] = v.y;
    tile[ii][a * 4 + 2] = v.z;
    tile[ii][a * 4 + 3] = v.w;
  }
  __syncthreads();

  ushort* xTb = xT + (size_t)b * GN * CIN;
#pragma unroll
  for (int p = 0; p < 4; ++p) {
    int gg = p * 16 + r;
    ushort4 u;
    u.x = f2bf(tile[a * 4 + 0][gg]);
    u.y = f2bf(tile[a * 4 + 1][gg]);
    u.z = f2bf(tile[a * 4 + 2][gg]);
    u.w = f2bf(tile[a * 4 + 3][gg]);
    *reinterpret_cast<ushort4*>(&xTb[(size_t)(g0 + gg) * CIN + i0 + a * 4]) = u;
  }
}

// ---------------------------------------------------------------------------
// Kernel 2: per-group GEMM.  One workgroup per g.
// A (xT) staged in LDS (XOR-swizzled), W streamed global->reg->bf16.
// setprio around MFMA cluster (no barriers in K-loop -> waves free-run).
// ---------------------------------------------------------------------------
__global__ __launch_bounds__(256) void k_group_gemm(
    const ushort* __restrict__ xT, const float* __restrict__ W,
    const float* __restrict__ bias, float* __restrict__ out,
    ushort* __restrict__ outT, int use_ws)
{
  const int g    = blockIdx.x;
  const int tid  = threadIdx.x;
  const int wave = tid >> 6;
  const int lane = tid & 63;

  __shared__ __align__(16) ushort lA[BATCH * CIN];  // 32 KB

#pragma unroll
  for (int r = 0; r < 8; ++r) {
    int b = r * 8 + (tid >> 5);
    int i = (tid & 31) * 8;
    int4 v = *reinterpret_cast<const int4*>(xT + ((size_t)b * GN + g) * CIN + i);
    *reinterpret_cast<int4*>(&lA[b * CIN + (i ^ ((b & 7) << 3))]) = v;
  }
  __syncthreads();

  const int oc = (wave << 6) + (lane & 15);
  const int kq = (lane >> 4) << 3;

  const float* wptr[4];
#pragma unroll
  for (int n = 0; n < 4; ++n)
    wptr[n] = W + ((size_t)g * COUT + oc + n * 16) * CIN + kq;

  f32x4 acc[4][4];
#pragma unroll
  for (int m = 0; m < 4; ++m)
#pragma unroll
    for (int n = 0; n < 4; ++n)
      acc[m][n] = {0.f, 0.f, 0.f, 0.f};

  float4 bnext[4][2];
#pragma unroll
  for (int n = 0; n < 4; ++n) {
    bnext[n][0] = *reinterpret_cast<const float4*>(wptr[n]);
    bnext[n][1] = *reinterpret_cast<const float4*>(wptr[n] + 4);
  }

#pragma unroll
  for (int ks = 0; ks < 8; ++ks) {
    float4 bcur[4][2];
#pragma unroll
    for (int n = 0; n < 4; ++n) {
      bcur[n][0] = bnext[n][0];
      bcur[n][1] = bnext[n][1];
    }
    if (ks < 7) {
#pragma unroll
      for (int n = 0; n < 4; ++n) {
        bnext[n][0] = *reinterpret_cast<const float4*>(wptr[n] + (ks + 1) * 32);
        bnext[n][1] = *reinterpret_cast<const float4*>(wptr[n] + (ks + 1) * 32 + 4);
      }
    }

    bf16x8 bfr[4];
#pragma unroll
    for (int n = 0; n < 4; ++n) {
      bfr[n][0] = (__bf16)bcur[n][0].x;
      bfr[n][1] = (__bf16)bcur[n][0].y;
      bfr[n][2] = (__bf16)bcur[n][0].z;
      bfr[n][3] = (__bf16)bcur[n][0].w;
      bfr[n][4] = (__bf16)bcur[n][1].x;
      bfr[n][5] = (__bf16)bcur[n][1].y;
      bfr[n][6] = (__bf16)bcur[n][1].z;
      bfr[n][7] = (__bf16)bcur[n][1].w;
    }

    bf16x8 afr[4];
    const int i0 = ks * 32 + kq;
#pragma unroll
    for (int m = 0; m < 4; ++m) {
      int row = m * 16 + (lane & 15);
      afr[m] = *reinterpret_cast<const bf16x8*>(
          &lA[row * CIN + (i0 ^ ((row & 7) << 3))]);
    }

    __builtin_amdgcn_s_setprio(1);
#pragma unroll
    for (int m = 0; m < 4; ++m)
#pragma unroll
      for (int n = 0; n < 4; ++n)
        acc[m][n] = __builtin_amdgcn_mfma_f32_16x16x32_bf16(
            afr[m], bfr[n], acc[m][n], 0, 0, 0);
    __builtin_amdgcn_s_setprio(0);
  }

  float bv[4];
#pragma unroll
  for (int n = 0; n < 4; ++n) bv[n] = bias[g * COUT + oc + n * 16];

  if (use_ws) {
#pragma unroll
    for (int m = 0; m < 4; ++m) {
#pragma unroll
      for (int n = 0; n < 4; ++n) {
        int o = oc + n * 16;
#pragma unroll
        for (int j = 0; j < 4; ++j) {
          int b = m * 16 + ((lane >> 4) << 2) + j;
          __hip_bfloat16 h = __float2bfloat16(acc[m][n][j] + bv[n]);
          outT[((size_t)b * GN + g) * COUT + o] = *reinterpret_cast<ushort*>(&h);
        }
      }
    }
  } else {
#pragma unroll
    for (int m = 0; m < 4; ++m) {
#pragma unroll
      for (int n = 0; n < 4; ++n) {
        int o = oc + n * 16;
#pragma unroll
        for (int j = 0; j < 4; ++j) {
          int b = m * 16 + ((lane >> 4) << 2) + j;
          out[((size_t)b * COUT + o) * GN + g] = acc[m][n][j] + bv[n];
        }
      }
    }
  }
}

// ---------------------------------------------------------------------------
// Kernel 3: transpose  outT[b][g][o] (bf16)  ->  out[b][o][g] (f32)
// 64x64 tile; ushort4 loads (8B/lane), float4 stores (16B/lane).
// ---------------------------------------------------------------------------
__global__ __launch_bounds__(256) void k_transpose_out(
    const ushort* __restrict__ outT, float* __restrict__ out)
{
  __shared__ float tile[64][65];  // [g][o]
  const int g0 = blockIdx.x * 64;
  const int o0 = blockIdx.y * 64;
  const int b  = blockIdx.z;
  const int t  = threadIdx.x;
  const int a  = t & 15;
  const int r  = t >> 4;

  const ushort* src = outT + (size_t)b * GN * COUT;
#pragma unroll
  for (int p = 0; p < 4; ++p) {
    int gl = p * 16 + r;
    ushort4 u = *reinterpret_cast<const ushort4*>(
        &src[(size_t)(g0 + gl) * COUT + o0 + a * 4]);
    tile[gl][a * 4 + 0] = bf2f(u.x);
    tile[gl][a * 4 + 1] = bf2f(u.y);
    tile[gl][a * 4 + 2] = bf2f(u.z);
    tile[gl][a * 4 + 3] = bf2f(u.w);
  }
  __syncthreads();

  float* dst = out + (size_t)b * COUT * GN;
#pragma unroll
  for (int p = 0; p < 4; ++p) {
    int ol = p * 16 + r;
    float4 v;
    v.x = tile[a * 4 + 0][ol];
    v.y = tile[a * 4 + 1][ol];
    v.z = tile[a * 4 + 2][ol];
    v.w = tile[a * 4 + 3][ol];
    *reinterpret_cast<float4*>(&dst[(size_t)(o0 + ol) * GN + g0 + a * 4]) = v;
  }
}

// ---------------------------------------------------------------------------
extern "C" void kernel_launch(void* const* d_in, const int* in_sizes, int n_in,
                              void* d_out, int out_size, void* d_ws, size_t ws_size,
                              hipStream_t stream) {
  const float* x  = (const float*)d_in[0];
  const float* W  = (const float*)d_in[1];
  const float* bs = (const float*)d_in[2];
  float* out      = (float*)d_out;

  const size_t xT_elems = (size_t)BATCH * GN * CIN;
  const size_t oT_elems = (size_t)BATCH * GN * COUT;
  const bool use_ws = ws_size >= (xT_elems + oT_elems) * sizeof(ushort);

  ushort* xT   = (ushort*)d_ws;
  ushort* outT = xT + xT_elems;

  dim3 grid1(GN / 64, CIN / 64, BATCH);
  k_transpose_convert<<<grid1, 256, 0, stream>>>(x, xT);
  k_group_gemm<<<GN, 256, 0, stream>>>(xT, W, bs, out,
                                       use_ws ? outT : nullptr,
                                       use_ws ? 1 : 0);
  if (use_ws) {
    dim3 grid3(GN / 64, COUT / 64, BATCH);
    k_transpose_out<<<grid3, 256, 0, stream>>>(outT, out);
  }
}

// Round 4
// 116.435 us; speedup vs baseline: 2.8151x; 1.0531x over previous
//
#include <hip/hip_runtime.h>
#include <hip/hip_bf16.h>

typedef __bf16 bf16x8 __attribute__((ext_vector_type(8)));
typedef float f32x4 __attribute__((ext_vector_type(4)));

#define GN    1024
#define BATCH 64
#define CIN   256
#define COUT  256
#define WSLICE 8192  // per wave, per buffer: 64 rows x 32 k x 4B

#define G_AS __attribute__((address_space(1)))
#define L_AS __attribute__((address_space(3)))

static __device__ __forceinline__ void gload16(const void* g, void* l) {
  __builtin_amdgcn_global_load_lds((const G_AS void*)g, (L_AS void*)l, 16, 0, 0);
}

static __device__ __forceinline__ ushort f2bf(float f) {
  __hip_bfloat16 h = __float2bfloat16(f);
  return *reinterpret_cast<ushort*>(&h);
}
static __device__ __forceinline__ float bf2f(ushort u) {
  uint v = (uint)u << 16;
  return *reinterpret_cast<float*>(&v);
}

// ---------------------------------------------------------------------------
// Kernel 1: transpose + convert  x[b][i][g] (f32) -> xT[b][g][i^((b&7)<<3)] (bf16)
// NOTE: xT is stored PRE-SWIZZLED in i (per b-row) so k2 can DMA it linearly
// into LDS (global_load_lds can't scatter; rule 21: swizzle source, not dest).
// ---------------------------------------------------------------------------
__global__ __launch_bounds__(256) void k_transpose_convert(
    const float* __restrict__ x, ushort* __restrict__ xT)
{
  __shared__ float tile[64][65];
  const int g0 = blockIdx.x * 64;
  const int i0 = blockIdx.y * 64;
  const int b  = blockIdx.z;
  const int t  = threadIdx.x;
  const int a  = t & 15;
  const int r  = t >> 4;
  const int key = (b & 7) << 3;  // element-XOR key for this b-row

  const float* xb = x + (size_t)b * CIN * GN;
#pragma unroll
  for (int p = 0; p < 4; ++p) {
    int ii = p * 16 + r;
    float4 v = *reinterpret_cast<const float4*>(
        &xb[(size_t)(i0 + ii) * GN + g0 + a * 4]);
    tile[ii][a * 4 + 0] = v.x;
    tile[ii][a * 4 + 1] = v.y;
    tile[ii][a * 4 + 2] = v.z;
    tile[ii][a * 4 + 3] = v.w;
  }
  __syncthreads();

  ushort* xTb = xT + (size_t)b * GN * CIN;
#pragma unroll
  for (int p = 0; p < 4; ++p) {
    int gg = p * 16 + r;
    ushort4 u;
    u.x = f2bf(tile[a * 4 + 0][gg]);
    u.y = f2bf(tile[a * 4 + 1][gg]);
    u.z = f2bf(tile[a * 4 + 2][gg]);
    u.w = f2bf(tile[a * 4 + 3][gg]);
    int isw = (i0 + a * 4) ^ key;  // key is mult of 8 -> ushort4 stays aligned
    *reinterpret_cast<ushort4*>(&xTb[(size_t)(g0 + gg) * CIN + isw]) = u;
  }
}

// ---------------------------------------------------------------------------
// Kernel 2: per-group GEMM, DMA-streamed.
// One block per g; wave w owns o in [64w, 64w+64).
// A: 32KB LDS, DMA'd linearly from pre-swizzled xT.
// W: per-wave private 2x8KB LDS dbuf, global_load_lds with counted vmcnt(8),
//    NO barriers in the K-loop. Source pre-swizzled so LDS reads are
//    byte^((row&7)<<4) bank-spread.
// ---------------------------------------------------------------------------
__global__ __launch_bounds__(256) void k_group_gemm(
    const ushort* __restrict__ xT, const float* __restrict__ W,
    const float* __restrict__ bias, float* __restrict__ out,
    ushort* __restrict__ outT, int use_ws)
{
  __shared__ __align__(16) unsigned char lds[BATCH * CIN * 2 + 4 * 2 * WSLICE]; // 96 KB
  ushort* lA        = (ushort*)lds;
  unsigned char* lW = lds + BATCH * CIN * 2;

  const int g    = blockIdx.x;
  const int tid  = threadIdx.x;
  const int wave = tid >> 6;
  const int lane = tid & 63;

  // ---- A DMA: wave w stages b-rows [16w,16w+16); 8 issues x 1KB ----
#pragma unroll
  for (int j = 0; j < 8; ++j) {
    int b = 16 * wave + 2 * j + (lane >> 5);
    const ushort* gsrc = xT + ((size_t)b * GN + g) * CIN + (lane & 31) * 8;
    ushort* ldst = lA + (16 * wave + 2 * j) * CIN;  // wave-uniform
    gload16(gsrc, ldst);
  }

  const float* wg = W + ((size_t)g * COUT + 64 * wave) * CIN;
  const int swz_src = ((lane & 7) ^ (lane >> 3)) << 4;  // byte offset in k-window
  const int wrow    = lane >> 3;

  // stage W slice ks (k window [32ks,32ks+32)) into per-wave buf
  auto stage_w = [&](int ks, int buf) {
    unsigned char* ldb = lW + wave * (2 * WSLICE) + buf * WSLICE;
    const unsigned char* gb = (const unsigned char*)wg + (size_t)ks * 128 + swz_src;
#pragma unroll
    for (int j = 0; j < 8; ++j) {
      gload16(gb + (size_t)(8 * j + wrow) * (CIN * 4), ldb + j * 1024);
    }
  };

  stage_w(0, 0);
  stage_w(1, 1);
  // retire A (oldest 8 of 24); W0/W1 stay in flight across the raw barrier
  asm volatile("s_waitcnt vmcnt(16)" ::: "memory");
  __builtin_amdgcn_sched_barrier(0);
  __builtin_amdgcn_s_barrier();

  const int arow = lane & 15;         // row-in-tile low bits
  const int colk = (lane >> 4) * 32;  // lane's k-octet byte offset
  const int kq   = (lane >> 4) << 3;  // same, in bf16 elements

  f32x4 acc[4][4];
#pragma unroll
  for (int m = 0; m < 4; ++m)
#pragma unroll
    for (int n = 0; n < 4; ++n)
      acc[m][n] = {0.f, 0.f, 0.f, 0.f};

#pragma unroll
  for (int ks = 0; ks < 8; ++ks) {
    if (ks < 7) { asm volatile("s_waitcnt vmcnt(8)" ::: "memory"); }
    else        { asm volatile("s_waitcnt vmcnt(0)" ::: "memory"); }
    __builtin_amdgcn_sched_barrier(0);

    unsigned char* wb = lW + wave * (2 * WSLICE) + (ks & 1) * WSLICE;

    bf16x8 bfr[4];
#pragma unroll
    for (int n = 0; n < 4; ++n) {
      int row = n * 16 + arow;
      int key = (row & 7) << 4;
      float4 f0 = *reinterpret_cast<const float4*>(wb + row * 128 + (colk ^ key));
      float4 f1 = *reinterpret_cast<const float4*>(wb + row * 128 + ((colk + 16) ^ key));
      bfr[n][0] = (__bf16)f0.x; bfr[n][1] = (__bf16)f0.y;
      bfr[n][2] = (__bf16)f0.z; bfr[n][3] = (__bf16)f0.w;
      bfr[n][4] = (__bf16)f1.x; bfr[n][5] = (__bf16)f1.y;
      bfr[n][6] = (__bf16)f1.z; bfr[n][7] = (__bf16)f1.w;
    }

    bf16x8 afr[4];
    const int i0 = ks * 32 + kq;
#pragma unroll
    for (int m = 0; m < 4; ++m) {
      int row = m * 16 + arow;
      afr[m] = *reinterpret_cast<const bf16x8*>(
          &lA[row * CIN + (i0 ^ ((row & 7) << 3))]);
    }

    __builtin_amdgcn_s_setprio(1);
#pragma unroll
    for (int m = 0; m < 4; ++m)
#pragma unroll
      for (int n = 0; n < 4; ++n)
        acc[m][n] = __builtin_amdgcn_mfma_f32_16x16x32_bf16(
            afr[m], bfr[n], acc[m][n], 0, 0, 0);
    __builtin_amdgcn_s_setprio(0);

    if (ks < 6) {
      // ensure this buffer's ds_reads retired before DMA overwrites it
      asm volatile("s_waitcnt lgkmcnt(0)" ::: "memory");
      __builtin_amdgcn_sched_barrier(0);
      stage_w(ks + 2, ks & 1);
    }
  }

  const int oc = 64 * wave + arow;
  float bv[4];
#pragma unroll
  for (int n = 0; n < 4; ++n) bv[n] = bias[g * COUT + oc + n * 16];

  if (use_ws) {
#pragma unroll
    for (int m = 0; m < 4; ++m) {
#pragma unroll
      for (int n = 0; n < 4; ++n) {
        int o = oc + n * 16;
#pragma unroll
        for (int j = 0; j < 4; ++j) {
          int b = m * 16 + ((lane >> 4) << 2) + j;
          __hip_bfloat16 h = __float2bfloat16(acc[m][n][j] + bv[n]);
          outT[((size_t)b * GN + g) * COUT + o] = *reinterpret_cast<ushort*>(&h);
        }
      }
    }
  } else {
#pragma unroll
    for (int m = 0; m < 4; ++m) {
#pragma unroll
      for (int n = 0; n < 4; ++n) {
        int o = oc + n * 16;
#pragma unroll
        for (int j = 0; j < 4; ++j) {
          int b = m * 16 + ((lane >> 4) << 2) + j;
          out[((size_t)b * COUT + o) * GN + g] = acc[m][n][j] + bv[n];
        }
      }
    }
  }
}

// ---------------------------------------------------------------------------
// Kernel 3: transpose  outT[b][g][o] (bf16) -> out[b][o][g] (f32)
// ---------------------------------------------------------------------------
__global__ __launch_bounds__(256) void k_transpose_out(
    const ushort* __restrict__ outT, float* __restrict__ out)
{
  __shared__ float tile[64][65];  // [g][o]
  const int g0 = blockIdx.x * 64;
  const int o0 = blockIdx.y * 64;
  const int b  = blockIdx.z;
  const int t  = threadIdx.x;
  const int a  = t & 15;
  const int r  = t >> 4;

  const ushort* src = outT + (size_t)b * GN * COUT;
#pragma unroll
  for (int p = 0; p < 4; ++p) {
    int gl = p * 16 + r;
    ushort4 u = *reinterpret_cast<const ushort4*>(
        &src[(size_t)(g0 + gl) * COUT + o0 + a * 4]);
    tile[gl][a * 4 + 0] = bf2f(u.x);
    tile[gl][a * 4 + 1] = bf2f(u.y);
    tile[gl][a * 4 + 2] = bf2f(u.z);
    tile[gl][a * 4 + 3] = bf2f(u.w);
  }
  __syncthreads();

  float* dst = out + (size_t)b * COUT * GN;
#pragma unroll
  for (int p = 0; p < 4; ++p) {
    int ol = p * 16 + r;
    float4 v;
    v.x = tile[a * 4 + 0][ol];
    v.y = tile[a * 4 + 1][ol];
    v.z = tile[a * 4 + 2][ol];
    v.w = tile[a * 4 + 3][ol];
    *reinterpret_cast<float4*>(&dst[(size_t)(o0 + ol) * GN + g0 + a * 4]) = v;
  }
}

// ---------------------------------------------------------------------------
extern "C" void kernel_launch(void* const* d_in, const int* in_sizes, int n_in,
                              void* d_out, int out_size, void* d_ws, size_t ws_size,
                              hipStream_t stream) {
  const float* x  = (const float*)d_in[0];
  const float* W  = (const float*)d_in[1];
  const float* bs = (const float*)d_in[2];
  float* out      = (float*)d_out;

  const size_t xT_elems = (size_t)BATCH * GN * CIN;
  const size_t oT_elems = (size_t)BATCH * GN * COUT;
  const bool use_ws = ws_size >= (xT_elems + oT_elems) * sizeof(ushort);

  ushort* xT   = (ushort*)d_ws;
  ushort* outT = xT + xT_elems;

  dim3 grid1(GN / 64, CIN / 64, BATCH);
  k_transpose_convert<<<grid1, 256, 0, stream>>>(x, xT);
  k_group_gemm<<<GN, 256, 0, stream>>>(xT, W, bs, out,
                                       use_ws ? outT : nullptr,
                                       use_ws ? 1 : 0);
  if (use_ws) {
    dim3 grid3(GN / 64, COUT / 64, BATCH);
    k_transpose_out<<<grid3, 256, 0, stream>>>(outT, out);
  }
}